// Round 6
// baseline (1016.523 us; speedup 1.0000x reference)
//
#include <hip/hip_runtime.h>
#include <hip/hip_bf16.h>

#define T_TOK 8192
#define D_DIM 1024
#define F_DIM 4096
#define E_NUM 8

typedef short s16x8 __attribute__((ext_vector_type(8)));
typedef float f32x4 __attribute__((ext_vector_type(4)));
typedef unsigned short u16x8 __attribute__((ext_vector_type(8)));

__device__ __forceinline__ unsigned short f2bf(float f) {
  union { float f; unsigned int u; } v; v.f = f;
  unsigned int u = v.u;
  return (unsigned short)((u + 0x7FFFu + ((u >> 16) & 1u)) >> 16);  // RNE
}

__device__ __forceinline__ void async16(const void* g, void* l) {
  __builtin_amdgcn_global_load_lds((const __attribute__((address_space(1))) void*)g,
                                   (__attribute__((address_space(3))) void*)l, 16, 0, 0);
}

// ---------------- RMSNorm + router (fp32) + top-2 compaction ----------------
__global__ __launch_bounds__(256) void norm_router_kernel(
    const float* __restrict__ hs, const float* __restrict__ nw,
    const float* __restrict__ gw, unsigned short* __restrict__ xb,
    float* __restrict__ logits_out, int* __restrict__ cnt,
    int* __restrict__ ilist, float* __restrict__ wlist) {
  int t = blockIdx.x;
  int tid = threadIdx.x;
  int lane = tid & 63, wid = tid >> 6;
  float4 v = ((const float4*)(hs + (size_t)t * D_DIM))[tid];
  float ss = v.x * v.x + v.y * v.y + v.z * v.z + v.w * v.w;
#pragma unroll
  for (int o = 32; o > 0; o >>= 1) ss += __shfl_xor(ss, o);
  __shared__ float red[4];
  __shared__ float pl[4][8];
  if (lane == 0) red[wid] = ss;
  __syncthreads();
  float ms = (red[0] + red[1] + red[2] + red[3]) * (1.0f / 1024.0f);
  float rs = rsqrtf(ms + 1e-6f);
  float4 wv = ((const float4*)nw)[tid];
  float x0 = v.x * rs * wv.x, x1 = v.y * rs * wv.y;
  float x2 = v.z * rs * wv.z, x3 = v.w * rs * wv.w;
  ((ushort4*)(xb + (size_t)t * D_DIM))[tid] =
      make_ushort4(f2bf(x0), f2bf(x1), f2bf(x2), f2bf(x3));
  float p[8];
#pragma unroll
  for (int e = 0; e < 8; ++e) {
    float4 g = ((const float4*)(gw + (size_t)e * D_DIM))[tid];
    p[e] = x0 * g.x + x1 * g.y + x2 * g.z + x3 * g.w;
  }
#pragma unroll
  for (int e = 0; e < 8; ++e) {
#pragma unroll
    for (int o = 32; o > 0; o >>= 1) p[e] += __shfl_xor(p[e], o);
  }
  if (lane == 0) {
#pragma unroll
    for (int e = 0; e < 8; ++e) pl[wid][e] = p[e];
  }
  __syncthreads();
  if (tid == 0) {
    float l[8];
#pragma unroll
    for (int e = 0; e < 8; ++e) {
      l[e] = pl[0][e] + pl[1][e] + pl[2][e] + pl[3][e];
      logits_out[(size_t)t * 8 + e] = l[e];
    }
    int i0 = 0; float b0 = l[0];
#pragma unroll
    for (int e = 1; e < 8; ++e) if (l[e] > b0) { b0 = l[e]; i0 = e; }
    int i1 = (i0 == 0) ? 1 : 0; float b1 = l[i1];
#pragma unroll
    for (int e = 0; e < 8; ++e) if (e != i0 && l[e] > b1) { b1 = l[e]; i1 = e; }
    float wa = 1.0f / (1.0f + __expf(b1 - b0));
    float wb = 1.0f / (1.0f + __expf(b0 - b1));
    int p0 = atomicAdd(&cnt[i0], 1);
    ilist[i0 * T_TOK + p0] = t * 2;     wlist[i0 * T_TOK + p0] = wa;
    int p1 = atomicAdd(&cnt[i1], 1);
    ilist[i1 * T_TOK + p1] = t * 2 + 1; wlist[i1 * T_TOK + p1] = wb;
  }
}

// ---- weight f32 -> bf16 transpose. w1/w3 -> w13t[e][8192][D] with 32-col
// ---- interleave; w2 -> w2t[e][D][F]
__global__ __launch_bounds__(256) void transpose_cvt_kernel(
    const float* __restrict__ w1, const float* __restrict__ w3,
    const float* __restrict__ w2, unsigned short* __restrict__ w13t,
    unsigned short* __restrict__ w2t) {
  __shared__ unsigned short tileS[64][72];  // [c-local][r-local], padded
  int bx = blockIdx.x;
  int tensor = bx >> 13;
  int e = (bx >> 10) & 7;
  int tl = bx & 1023;
  const float* src; int C, tr, tc;
  if (tensor == 0) {
    src = w1 + (size_t)e * D_DIM * F_DIM; C = F_DIM; tr = tl >> 6; tc = tl & 63;
  } else if (tensor == 1) {
    src = w3 + (size_t)e * D_DIM * F_DIM; C = F_DIM; tr = tl >> 6; tc = tl & 63;
  } else {
    src = w2 + (size_t)e * F_DIM * D_DIM; C = D_DIM; tr = tl >> 4; tc = tl & 15;
  }
  int r0 = tr * 64, c0 = tc * 64;
  int tid = threadIdx.x;
  int rr = tid >> 4, ccb = (tid & 15) * 4;
#pragma unroll
  for (int i = 0; i < 4; ++i) {
    int r = rr + i * 16;
    float4 v = *(const float4*)(src + (size_t)(r0 + r) * C + c0 + ccb);
    tileS[ccb + 0][r] = f2bf(v.x);
    tileS[ccb + 1][r] = f2bf(v.y);
    tileS[ccb + 2][r] = f2bf(v.z);
    tileS[ccb + 3][r] = f2bf(v.w);
  }
  __syncthreads();
  int row = tid >> 2, col = (tid & 3) * 16;
  unsigned short* dp;
  if (tensor < 2) {
    int f = c0 + row;
    int prow = ((f >> 5) * 64) + (f & 31) + (tensor == 1 ? 32 : 0);
    dp = w13t + ((size_t)e * 8192 + prow) * D_DIM + r0 + col;
  } else {
    dp = w2t + ((size_t)e * D_DIM + c0 + row) * F_DIM + r0 + col;
  }
  u16x8 v0, v1;
#pragma unroll
  for (int j = 0; j < 8; ++j) { v0[j] = tileS[row][col + j]; v1[j] = tileS[row][col + 8 + j]; }
  *(u16x8*)dp = v0;
  *(u16x8*)(dp + 8) = v1;
}

// ---- shared MFMA helper: 4 MFMAs of one A-frag against b0..b3 ----
#define MFMA4(AI_, M_)                                                           \
  acc[M_][0] = __builtin_amdgcn_mfma_f32_16x16x32_bf16(AI_, b0, acc[M_][0], 0, 0, 0); \
  acc[M_][1] = __builtin_amdgcn_mfma_f32_16x16x32_bf16(AI_, b1, acc[M_][1], 0, 0, 0); \
  acc[M_][2] = __builtin_amdgcn_mfma_f32_16x16x32_bf16(AI_, b2, acc[M_][2], 0, 0, 0); \
  acc[M_][3] = __builtin_amdgcn_mfma_f32_16x16x32_bf16(AI_, b3, acc[M_][3], 0, 0, 0);

#define PHASE_TAIL()                                                             \
  __builtin_amdgcn_s_barrier();                                                  \
  asm volatile("s_waitcnt lgkmcnt(0)" ::: "memory");                             \
  __builtin_amdgcn_sched_barrier(0);                                             \
  __builtin_amdgcn_s_setprio(1);

#define PHASE_END()                                                              \
  __builtin_amdgcn_s_setprio(0);                                                 \
  __builtin_amdgcn_s_barrier();

// One K-tile (BK=64) = 4 phases. CUR_/NXT_ compile-time 0/1. KT1_ = tile staged.
#define G_ITER(CUR_, NXT_, KT1_, DOST_)                                          \
  {                                                                              \
    const unsigned short* Ac = &As[CUR_][0];                                     \
    const unsigned short* Bc = &Bs[CUR_][0];                                     \
    s16x8 a0, a1, a2, a3, b0, b1, b2, b3;                                        \
    /* p0: a(lo,ks0)+b(ks0); stage A(t+1) */                                     \
    a0 = *(const s16x8*)(Ac + aoff[0]); a1 = *(const s16x8*)(Ac + aoff[1]);      \
    a2 = *(const s16x8*)(Ac + aoff[2]); a3 = *(const s16x8*)(Ac + aoff[3]);      \
    b0 = *(const s16x8*)(Bc + boff[0]); b1 = *(const s16x8*)(Bc + boff[1]);      \
    b2 = *(const s16x8*)(Bc + boff[2]); b3 = *(const s16x8*)(Bc + boff[3]);      \
    if (DOST_) {                                                                 \
      int ko = (KT1_) * 64;                                                      \
      async16(ap0 + ko, &As[NXT_][tid * 8]);                                     \
      async16(ap1 + ko, &As[NXT_][4096 + tid * 8]);                              \
      async16(ap2 + ko, &As[NXT_][8192 + tid * 8]);                              \
      async16(ap3 + ko, &As[NXT_][12288 + tid * 8]);                             \
    }                                                                            \
    PHASE_TAIL()                                                                 \
    MFMA4(a0, 0) MFMA4(a1, 1) MFMA4(a2, 2) MFMA4(a3, 3)                          \
    PHASE_END()                                                                  \
    /* p1: a(hi,ks0); stage B(t+1) */                                           \
    a0 = *(const s16x8*)(Ac + aoff[4]); a1 = *(const s16x8*)(Ac + aoff[5]);      \
    a2 = *(const s16x8*)(Ac + aoff[6]); a3 = *(const s16x8*)(Ac + aoff[7]);      \
    if (DOST_) {                                                                 \
      int ko = (KT1_) * 64;                                                      \
      async16(bp0 + ko, &Bs[NXT_][tid * 8]);                                     \
      async16(bp1 + ko, &Bs[NXT_][4096 + tid * 8]);                              \
      async16(bp2 + ko, &Bs[NXT_][8192 + tid * 8]);                              \
      async16(bp3 + ko, &Bs[NXT_][12288 + tid * 8]);                             \
    }                                                                            \
    PHASE_TAIL()                                                                 \
    MFMA4(a0, 4) MFMA4(a1, 5) MFMA4(a2, 6) MFMA4(a3, 7)                          \
    PHASE_END()                                                                  \
    /* p2: a(lo,ks1)+b(ks1) */                                                   \
    a0 = *(const s16x8*)(Ac + (aoff[0] ^ 32)); a1 = *(const s16x8*)(Ac + (aoff[1] ^ 32)); \
    a2 = *(const s16x8*)(Ac + (aoff[2] ^ 32)); a3 = *(const s16x8*)(Ac + (aoff[3] ^ 32)); \
    b0 = *(const s16x8*)(Bc + (boff[0] ^ 32)); b1 = *(const s16x8*)(Bc + (boff[1] ^ 32)); \
    b2 = *(const s16x8*)(Bc + (boff[2] ^ 32)); b3 = *(const s16x8*)(Bc + (boff[3] ^ 32)); \
    PHASE_TAIL()                                                                 \
    MFMA4(a0, 0) MFMA4(a1, 1) MFMA4(a2, 2) MFMA4(a3, 3)                          \
    PHASE_END()                                                                  \
    /* p3: a(hi,ks1); vmcnt before closing barrier (stage handoff) */            \
    a0 = *(const s16x8*)(Ac + (aoff[4] ^ 32)); a1 = *(const s16x8*)(Ac + (aoff[5] ^ 32)); \
    a2 = *(const s16x8*)(Ac + (aoff[6] ^ 32)); a3 = *(const s16x8*)(Ac + (aoff[7] ^ 32)); \
    PHASE_TAIL()                                                                 \
    MFMA4(a0, 4) MFMA4(a1, 5) MFMA4(a2, 6) MFMA4(a3, 7)                          \
    __builtin_amdgcn_s_setprio(0);                                               \
    asm volatile("s_waitcnt vmcnt(0)" ::: "memory");                             \
    __builtin_amdgcn_s_barrier();                                                \
  }

// ---- GEMM1: H = silu(Xe@W1e)*(Xe@W3e). 256x256, 8 waves, 4-phase/K-tile ----
__global__ __launch_bounds__(512, 2) void gemm1_kernel(
    const unsigned short* __restrict__ xb, const unsigned short* __restrict__ w13t,
    unsigned short* __restrict__ H, const int* __restrict__ cnt,
    const int* __restrict__ ilist) {
  int flat = blockIdx.x;       // 8192 blocks
  int e = flat & 7;            // expert == XCD
  int work = flat >> 3;
  int rt = work & 31;
  int ft = work >> 5;          // 0..31
  int ne = cnt[e];
  int r0 = rt * 256;
  if (r0 >= ne) return;
  __shared__ __align__(16) unsigned short As[2][16384];  // [256][64] per buf
  __shared__ __align__(16) unsigned short Bs[2][16384];
  __shared__ int toks[256];
  int tid = threadIdx.x, lane = tid & 63, w = tid >> 6;
  if (tid < 256) toks[tid] = ilist[e * T_TOK + min(r0 + tid, ne - 1)];
  __syncthreads();
  const unsigned short* bpanel = w13t + ((size_t)e * 8192 + ft * 256) * D_DIM;
  // staging: thread covers rows q*64+rr (q=0..3), 16B chunk ch, swizzled source
  int rr = tid >> 3, ch = tid & 7;
  int coff = ((ch ^ (rr & 7)) * 8);
  const unsigned short* ap0 = xb + (size_t)(toks[rr] >> 1) * D_DIM + coff;
  const unsigned short* ap1 = xb + (size_t)(toks[64 + rr] >> 1) * D_DIM + coff;
  const unsigned short* ap2 = xb + (size_t)(toks[128 + rr] >> 1) * D_DIM + coff;
  const unsigned short* ap3 = xb + (size_t)(toks[192 + rr] >> 1) * D_DIM + coff;
  const unsigned short* bp0 = bpanel + (size_t)rr * D_DIM + coff;
  const unsigned short* bp1 = bpanel + (size_t)(64 + rr) * D_DIM + coff;
  const unsigned short* bp2 = bpanel + (size_t)(128 + rr) * D_DIM + coff;
  const unsigned short* bp3 = bpanel + (size_t)(192 + rr) * D_DIM + coff;
  int wr = w >> 2, wc = w & 3;           // 2 x 4 wave grid, tile 128x64
  int lr = lane & 15, lc = lane >> 4;
  int aoff[8], boff[4];
#pragma unroll
  for (int m = 0; m < 8; ++m) {
    int row = wr * 128 + m * 16 + lr;
    aoff[m] = row * 64 + ((lc ^ (row & 7)) * 8);
  }
#pragma unroll
  for (int n = 0; n < 4; ++n) {
    int row = wc * 64 + n * 16 + lr;
    boff[n] = row * 64 + ((lc ^ (row & 7)) * 8);
  }
  f32x4 acc[8][4] = {};
  // prologue: stage tile 0 into buf 0
  async16(ap0, &As[0][tid * 8]);       async16(ap1, &As[0][4096 + tid * 8]);
  async16(ap2, &As[0][8192 + tid * 8]); async16(ap3, &As[0][12288 + tid * 8]);
  async16(bp0, &Bs[0][tid * 8]);       async16(bp1, &Bs[0][4096 + tid * 8]);
  async16(bp2, &Bs[0][8192 + tid * 8]); async16(bp3, &Bs[0][12288 + tid * 8]);
  asm volatile("s_waitcnt vmcnt(0)" ::: "memory");
  __builtin_amdgcn_s_barrier();
  for (int kt = 0; kt < 14; kt += 2) {   // NK=16
    G_ITER(0, 1, kt + 1, 1)
    G_ITER(1, 0, kt + 2, 1)
  }
  G_ITER(0, 1, 15, 1)
  G_ITER(1, 0, 16, 0)

  int g4 = lane >> 4, cl = lane & 15;
  int fbase = (4 * ft + wc) * 32;   // 32 f-cols per wave (w1 n=0,1 ; w3 n=2,3)
#pragma unroll
  for (int m = 0; m < 8; ++m) {
#pragma unroll
    for (int j = 0; j < 4; ++j) {
      int rloc = wr * 128 + m * 16 + g4 * 4 + j;
      if (r0 + rloc < ne) {
        unsigned short* hp = H + (size_t)toks[rloc] * F_DIM + fbase + cl;
#pragma unroll
        for (int n = 0; n < 2; ++n) {
          float c1 = acc[m][n][j], c3 = acc[m][n + 2][j];
          float h = c1 / (1.0f + __expf(-c1)) * c3;
          hp[n * 16] = f2bf(h);
        }
      }
    }
  }
}

// ---- GEMM2: out += w * (He @ W2e). 256x256, 8 waves, 4-phase/K-tile ----
__global__ __launch_bounds__(512, 2) void gemm2_kernel(
    const unsigned short* __restrict__ H, const unsigned short* __restrict__ w2t,
    const int* __restrict__ cnt, const int* __restrict__ ilist,
    const float* __restrict__ wlist, float* __restrict__ out) {
  int flat = blockIdx.x;       // 1024 blocks
  int e = flat & 7;
  int work = flat >> 3;
  int rt = work & 31;
  int nt = work >> 5;          // 0..3
  int ne = cnt[e];
  int r0 = rt * 256;
  if (r0 >= ne) return;
  __shared__ __align__(16) unsigned short As[2][16384];
  __shared__ __align__(16) unsigned short Bs[2][16384];
  __shared__ int toks[256];
  __shared__ float wts[256];
  int tid = threadIdx.x, lane = tid & 63, w = tid >> 6;
  if (tid < 256) {
    int idx = e * T_TOK + min(r0 + tid, ne - 1);
    toks[tid] = ilist[idx];
    wts[tid] = wlist[idx];
  }
  __syncthreads();
  const unsigned short* bpanel = w2t + ((size_t)e * D_DIM + nt * 256) * F_DIM;
  int rr = tid >> 3, ch = tid & 7;
  int coff = ((ch ^ (rr & 7)) * 8);
  const unsigned short* ap0 = H + (size_t)toks[rr] * F_DIM + coff;
  const unsigned short* ap1 = H + (size_t)toks[64 + rr] * F_DIM + coff;
  const unsigned short* ap2 = H + (size_t)toks[128 + rr] * F_DIM + coff;
  const unsigned short* ap3 = H + (size_t)toks[192 + rr] * F_DIM + coff;
  const unsigned short* bp0 = bpanel + (size_t)rr * F_DIM + coff;
  const unsigned short* bp1 = bpanel + (size_t)(64 + rr) * F_DIM + coff;
  const unsigned short* bp2 = bpanel + (size_t)(128 + rr) * F_DIM + coff;
  const unsigned short* bp3 = bpanel + (size_t)(192 + rr) * F_DIM + coff;
  int wr = w >> 2, wc = w & 3;
  int lr = lane & 15, lc = lane >> 4;
  int aoff[8], boff[4];
#pragma unroll
  for (int m = 0; m < 8; ++m) {
    int row = wr * 128 + m * 16 + lr;
    aoff[m] = row * 64 + ((lc ^ (row & 7)) * 8);
  }
#pragma unroll
  for (int n = 0; n < 4; ++n) {
    int row = wc * 64 + n * 16 + lr;
    boff[n] = row * 64 + ((lc ^ (row & 7)) * 8);
  }
  f32x4 acc[8][4] = {};
  async16(ap0, &As[0][tid * 8]);       async16(ap1, &As[0][4096 + tid * 8]);
  async16(ap2, &As[0][8192 + tid * 8]); async16(ap3, &As[0][12288 + tid * 8]);
  async16(bp0, &Bs[0][tid * 8]);       async16(bp1, &Bs[0][4096 + tid * 8]);
  async16(bp2, &Bs[0][8192 + tid * 8]); async16(bp3, &Bs[0][12288 + tid * 8]);
  asm volatile("s_waitcnt vmcnt(0)" ::: "memory");
  __builtin_amdgcn_s_barrier();
  for (int kt = 0; kt < 62; kt += 2) {   // NK=64
    G_ITER(0, 1, kt + 1, 1)
    G_ITER(1, 0, kt + 2, 1)
  }
  G_ITER(0, 1, 63, 1)
  G_ITER(1, 0, 64, 0)

  int g4 = lane >> 4, cl = lane & 15;
#pragma unroll
  for (int m = 0; m < 8; ++m) {
#pragma unroll
    for (int j = 0; j < 4; ++j) {
      int rloc = wr * 128 + m * 16 + g4 * 4 + j;
      if (r0 + rloc < ne) {
        int tok = toks[rloc] >> 1;
        float ww = wts[rloc];
        float* op = out + (size_t)tok * D_DIM + nt * 256 + wc * 64 + cl;
#pragma unroll
        for (int n = 0; n < 4; ++n)
          unsafeAtomicAdd(op + n * 16, ww * acc[m][n][j]);
      }
    }
  }
}

extern "C" void kernel_launch(void* const* d_in, const int* in_sizes, int n_in,
                              void* d_out, int out_size, void* d_ws, size_t ws_size,
                              hipStream_t stream) {
  const float* hs = (const float*)d_in[0];
  const float* nw = (const float*)d_in[1];
  const float* gw = (const float*)d_in[2];
  const float* w1 = (const float*)d_in[3];
  const float* w3 = (const float*)d_in[4];
  const float* w2 = (const float*)d_in[5];
  float* out = (float*)d_out;
  float* logits_out = out + (size_t)T_TOK * D_DIM;

  char* ws = (char*)d_ws;
  unsigned short* xb   = (unsigned short*)(ws);                 // 16 MiB bf16 x
  unsigned short* w13t = (unsigned short*)(ws + 16777216ull);   // 128 MiB [E][8192][D]
  unsigned short* w2t  = (unsigned short*)(ws + 150994944ull);  // 64 MiB [E][D][F]
  unsigned short* H    = (unsigned short*)(ws + 218103808ull);  // 128 MiB [2T][F]
  int*   ilist = (int*)(ws + 352321536ull);                     // [E][T] int
  float* wlist = (float*)(ws + 352583680ull);                   // [E][T] f32
  int*   cnt   = (int*)(ws + 352845824ull);                     // [E] int

  hipMemsetAsync(d_out, 0, (size_t)out_size * sizeof(float), stream);
  hipMemsetAsync(cnt, 0, E_NUM * sizeof(int), stream);
  norm_router_kernel<<<T_TOK, 256, 0, stream>>>(hs, nw, gw, xb, logits_out, cnt, ilist, wlist);
  transpose_cvt_kernel<<<3 * E_NUM * 1024, 256, 0, stream>>>(w1, w3, w2, w13t, w2t);
  gemm1_kernel<<<E_NUM * 32 * 32, 512, 0, stream>>>(xb, w13t, H, cnt, ilist);
  gemm2_kernel<<<E_NUM * 32 * 4, 512, 0, stream>>>(H, w2t, cnt, ilist, wlist, out);
}

// Round 7
// 1008.642 us; speedup vs baseline: 1.0078x; 1.0078x over previous
//
#include <hip/hip_runtime.h>
#include <hip/hip_bf16.h>

#define T_TOK 8192
#define D_DIM 1024
#define F_DIM 4096
#define E_NUM 8

typedef short s16x8 __attribute__((ext_vector_type(8)));
typedef float f32x4 __attribute__((ext_vector_type(4)));
typedef unsigned short u16x8 __attribute__((ext_vector_type(8)));

__device__ __forceinline__ unsigned short f2bf(float f) {
  union { float f; unsigned int u; } v; v.f = f;
  unsigned int u = v.u;
  return (unsigned short)((u + 0x7FFFu + ((u >> 16) & 1u)) >> 16);  // RNE
}

__device__ __forceinline__ void async16(const void* g, void* l) {
  __builtin_amdgcn_global_load_lds((const __attribute__((address_space(1))) void*)g,
                                   (__attribute__((address_space(3))) void*)l, 16, 0, 0);
}

// ---------------- RMSNorm + router (fp32) + top-2 compaction ----------------
__global__ __launch_bounds__(256) void norm_router_kernel(
    const float* __restrict__ hs, const float* __restrict__ nw,
    const float* __restrict__ gw, unsigned short* __restrict__ xb,
    float* __restrict__ logits_out, int* __restrict__ cnt,
    int* __restrict__ ilist, float* __restrict__ wlist) {
  int t = blockIdx.x;
  int tid = threadIdx.x;
  int lane = tid & 63, wid = tid >> 6;
  float4 v = ((const float4*)(hs + (size_t)t * D_DIM))[tid];
  float ss = v.x * v.x + v.y * v.y + v.z * v.z + v.w * v.w;
#pragma unroll
  for (int o = 32; o > 0; o >>= 1) ss += __shfl_xor(ss, o);
  __shared__ float red[4];
  __shared__ float pl[4][8];
  if (lane == 0) red[wid] = ss;
  __syncthreads();
  float ms = (red[0] + red[1] + red[2] + red[3]) * (1.0f / 1024.0f);
  float rs = rsqrtf(ms + 1e-6f);
  float4 wv = ((const float4*)nw)[tid];
  float x0 = v.x * rs * wv.x, x1 = v.y * rs * wv.y;
  float x2 = v.z * rs * wv.z, x3 = v.w * rs * wv.w;
  ((ushort4*)(xb + (size_t)t * D_DIM))[tid] =
      make_ushort4(f2bf(x0), f2bf(x1), f2bf(x2), f2bf(x3));
  float p[8];
#pragma unroll
  for (int e = 0; e < 8; ++e) {
    float4 g = ((const float4*)(gw + (size_t)e * D_DIM))[tid];
    p[e] = x0 * g.x + x1 * g.y + x2 * g.z + x3 * g.w;
  }
#pragma unroll
  for (int e = 0; e < 8; ++e) {
#pragma unroll
    for (int o = 32; o > 0; o >>= 1) p[e] += __shfl_xor(p[e], o);
  }
  if (lane == 0) {
#pragma unroll
    for (int e = 0; e < 8; ++e) pl[wid][e] = p[e];
  }
  __syncthreads();
  if (tid == 0) {
    float l[8];
#pragma unroll
    for (int e = 0; e < 8; ++e) {
      l[e] = pl[0][e] + pl[1][e] + pl[2][e] + pl[3][e];
      logits_out[(size_t)t * 8 + e] = l[e];
    }
    int i0 = 0; float b0 = l[0];
#pragma unroll
    for (int e = 1; e < 8; ++e) if (l[e] > b0) { b0 = l[e]; i0 = e; }
    int i1 = (i0 == 0) ? 1 : 0; float b1 = l[i1];
#pragma unroll
    for (int e = 0; e < 8; ++e) if (e != i0 && l[e] > b1) { b1 = l[e]; i1 = e; }
    float wa = 1.0f / (1.0f + __expf(b1 - b0));
    float wb = 1.0f / (1.0f + __expf(b0 - b1));
    int p0 = atomicAdd(&cnt[i0], 1);
    ilist[i0 * T_TOK + p0] = t * 2;     wlist[i0 * T_TOK + p0] = wa;
    int p1 = atomicAdd(&cnt[i1], 1);
    ilist[i1 * T_TOK + p1] = t * 2 + 1; wlist[i1 * T_TOK + p1] = wb;
  }
}

// ---- weight f32 -> bf16 transpose. w1/w3 -> w13t[e][8192][D] with 32-col
// ---- interleave; w2 -> w2t[e][D][F]
__global__ __launch_bounds__(256) void transpose_cvt_kernel(
    const float* __restrict__ w1, const float* __restrict__ w3,
    const float* __restrict__ w2, unsigned short* __restrict__ w13t,
    unsigned short* __restrict__ w2t) {
  __shared__ unsigned short tileS[64][72];  // [c-local][r-local], padded
  int bx = blockIdx.x;
  int tensor = bx >> 13;
  int e = (bx >> 10) & 7;
  int tl = bx & 1023;
  const float* src; int C, tr, tc;
  if (tensor == 0) {
    src = w1 + (size_t)e * D_DIM * F_DIM; C = F_DIM; tr = tl >> 6; tc = tl & 63;
  } else if (tensor == 1) {
    src = w3 + (size_t)e * D_DIM * F_DIM; C = F_DIM; tr = tl >> 6; tc = tl & 63;
  } else {
    src = w2 + (size_t)e * F_DIM * D_DIM; C = D_DIM; tr = tl >> 4; tc = tl & 15;
  }
  int r0 = tr * 64, c0 = tc * 64;
  int tid = threadIdx.x;
  int rr = tid >> 4, ccb = (tid & 15) * 4;
#pragma unroll
  for (int i = 0; i < 4; ++i) {
    int r = rr + i * 16;
    float4 v = *(const float4*)(src + (size_t)(r0 + r) * C + c0 + ccb);
    tileS[ccb + 0][r] = f2bf(v.x);
    tileS[ccb + 1][r] = f2bf(v.y);
    tileS[ccb + 2][r] = f2bf(v.z);
    tileS[ccb + 3][r] = f2bf(v.w);
  }
  __syncthreads();
  int row = tid >> 2, col = (tid & 3) * 16;
  unsigned short* dp;
  if (tensor < 2) {
    int f = c0 + row;
    int prow = ((f >> 5) * 64) + (f & 31) + (tensor == 1 ? 32 : 0);
    dp = w13t + ((size_t)e * 8192 + prow) * D_DIM + r0 + col;
  } else {
    dp = w2t + ((size_t)e * D_DIM + c0 + row) * F_DIM + r0 + col;
  }
  u16x8 v0, v1;
#pragma unroll
  for (int j = 0; j < 8; ++j) { v0[j] = tileS[row][col + j]; v1[j] = tileS[row][col + 8 + j]; }
  *(u16x8*)dp = v0;
  *(u16x8*)(dp + 8) = v1;
}

// ---- shared MFMA helper: 4 MFMAs of one A-frag against b0..b3 ----
#define MFMA4(AI_, M_)                                                           \
  acc[M_][0] = __builtin_amdgcn_mfma_f32_16x16x32_bf16(AI_, b0, acc[M_][0], 0, 0, 0); \
  acc[M_][1] = __builtin_amdgcn_mfma_f32_16x16x32_bf16(AI_, b1, acc[M_][1], 0, 0, 0); \
  acc[M_][2] = __builtin_amdgcn_mfma_f32_16x16x32_bf16(AI_, b2, acc[M_][2], 0, 0, 0); \
  acc[M_][3] = __builtin_amdgcn_mfma_f32_16x16x32_bf16(AI_, b3, acc[M_][3], 0, 0, 0);

#define LGKM0()                                                                  \
  asm volatile("s_waitcnt lgkmcnt(0)" ::: "memory");                             \
  __builtin_amdgcn_sched_barrier(0);

// One K-tile (BK=64). Counted-vmcnt schedule:
//  p0: read a0-7(ks0)+b0-3(ks0) | BAR | MFMA lo x b(ks0)
//  p1: read c0-3 = a0-3(ks1)    | BAR | MFMA hi x b(ks0)
//  p2: read a4-7(ks1)+b(ks1)    | BAR | MFMA lo(ks1) x b(ks1)
//  p3: stage tile t+2 -> buf[CUR] (reads of CUR done by p2) ; MFMA hi(ks1) ;
//      vmcnt(VMC) ; BAR      (VMC=8 steady: t+1's 8 loads stay in flight)
#define G_ITER(CUR_, KT2_, DOST_, VMC_)                                          \
  {                                                                              \
    const unsigned short* Ac = &As[CUR_][0];                                     \
    const unsigned short* Bc = &Bs[CUR_][0];                                     \
    s16x8 a0, a1, a2, a3, a4, a5, a6, a7, b0, b1, b2, b3, c0, c1, c2, c3;        \
    /* p0 */                                                                     \
    a0 = *(const s16x8*)(Ac + aoff[0]); a1 = *(const s16x8*)(Ac + aoff[1]);      \
    a2 = *(const s16x8*)(Ac + aoff[2]); a3 = *(const s16x8*)(Ac + aoff[3]);      \
    a4 = *(const s16x8*)(Ac + aoff[4]); a5 = *(const s16x8*)(Ac + aoff[5]);      \
    a6 = *(const s16x8*)(Ac + aoff[6]); a7 = *(const s16x8*)(Ac + aoff[7]);      \
    b0 = *(const s16x8*)(Bc + boff[0]); b1 = *(const s16x8*)(Bc + boff[1]);      \
    b2 = *(const s16x8*)(Bc + boff[2]); b3 = *(const s16x8*)(Bc + boff[3]);      \
    __builtin_amdgcn_s_barrier();                                                \
    LGKM0()                                                                      \
    __builtin_amdgcn_s_setprio(1);                                               \
    MFMA4(a0, 0) MFMA4(a1, 1) MFMA4(a2, 2) MFMA4(a3, 3)                          \
    __builtin_amdgcn_s_setprio(0);                                               \
    __builtin_amdgcn_s_barrier();                                                \
    /* p1 */                                                                     \
    c0 = *(const s16x8*)(Ac + (aoff[0] ^ 32)); c1 = *(const s16x8*)(Ac + (aoff[1] ^ 32)); \
    c2 = *(const s16x8*)(Ac + (aoff[2] ^ 32)); c3 = *(const s16x8*)(Ac + (aoff[3] ^ 32)); \
    __builtin_amdgcn_s_barrier();                                                \
    LGKM0()                                                                      \
    __builtin_amdgcn_s_setprio(1);                                               \
    MFMA4(a4, 4) MFMA4(a5, 5) MFMA4(a6, 6) MFMA4(a7, 7)                          \
    __builtin_amdgcn_s_setprio(0);                                               \
    __builtin_amdgcn_s_barrier();                                                \
    /* p2 */                                                                     \
    a4 = *(const s16x8*)(Ac + (aoff[4] ^ 32)); a5 = *(const s16x8*)(Ac + (aoff[5] ^ 32)); \
    a6 = *(const s16x8*)(Ac + (aoff[6] ^ 32)); a7 = *(const s16x8*)(Ac + (aoff[7] ^ 32)); \
    b0 = *(const s16x8*)(Bc + (boff[0] ^ 32)); b1 = *(const s16x8*)(Bc + (boff[1] ^ 32)); \
    b2 = *(const s16x8*)(Bc + (boff[2] ^ 32)); b3 = *(const s16x8*)(Bc + (boff[3] ^ 32)); \
    __builtin_amdgcn_s_barrier();                                                \
    LGKM0()                                                                      \
    __builtin_amdgcn_s_setprio(1);                                               \
    MFMA4(c0, 0) MFMA4(c1, 1) MFMA4(c2, 2) MFMA4(c3, 3)                          \
    __builtin_amdgcn_s_setprio(0);                                               \
    __builtin_amdgcn_s_barrier();                                                \
    /* p3: stage t+2 into buf[CUR] (all CUR reads completed by p2) */            \
    if (DOST_) {                                                                 \
      int ko = (KT2_) * 64;                                                      \
      async16(ap0 + ko, &As[CUR_][tid * 8]);                                     \
      async16(ap1 + ko, &As[CUR_][4096 + tid * 8]);                              \
      async16(ap2 + ko, &As[CUR_][8192 + tid * 8]);                              \
      async16(ap3 + ko, &As[CUR_][12288 + tid * 8]);                             \
      async16(bp0 + ko, &Bs[CUR_][tid * 8]);                                     \
      async16(bp1 + ko, &Bs[CUR_][4096 + tid * 8]);                              \
      async16(bp2 + ko, &Bs[CUR_][8192 + tid * 8]);                              \
      async16(bp3 + ko, &Bs[CUR_][12288 + tid * 8]);                             \
    }                                                                            \
    __builtin_amdgcn_s_setprio(1);                                               \
    MFMA4(a4, 4) MFMA4(a5, 5) MFMA4(a6, 6) MFMA4(a7, 7)                          \
    __builtin_amdgcn_s_setprio(0);                                               \
    asm volatile("s_waitcnt vmcnt(" VMC_ ")" ::: "memory");                      \
    __builtin_amdgcn_s_barrier();                                                \
  }

// ---- GEMM1: H = silu(Xe@W1e)*(Xe@W3e). 256x256, 8 waves, counted-vmcnt ----
__global__ __launch_bounds__(512, 2) void gemm1_kernel(
    const unsigned short* __restrict__ xb, const unsigned short* __restrict__ w13t,
    unsigned short* __restrict__ H, const int* __restrict__ cnt,
    const int* __restrict__ ilist) {
  int flat = blockIdx.x;       // 8192 blocks
  int e = flat & 7;            // expert == XCD
  int work = flat >> 3;
  int rt = work & 31;
  int ft = work >> 5;          // 0..31
  int ne = cnt[e];
  int r0 = rt * 256;
  if (r0 >= ne) return;
  __shared__ __align__(16) unsigned short As[2][16384];  // [256][64] per buf
  __shared__ __align__(16) unsigned short Bs[2][16384];
  __shared__ int toks[256];
  int tid = threadIdx.x, lane = tid & 63, w = tid >> 6;
  if (tid < 256) toks[tid] = ilist[e * T_TOK + min(r0 + tid, ne - 1)];
  __syncthreads();
  const unsigned short* bpanel = w13t + ((size_t)e * 8192 + ft * 256) * D_DIM;
  int rr = tid >> 3, ch = tid & 7;
  int coff = ((ch ^ (rr & 7)) * 8);
  const unsigned short* ap0 = xb + (size_t)(toks[rr] >> 1) * D_DIM + coff;
  const unsigned short* ap1 = xb + (size_t)(toks[64 + rr] >> 1) * D_DIM + coff;
  const unsigned short* ap2 = xb + (size_t)(toks[128 + rr] >> 1) * D_DIM + coff;
  const unsigned short* ap3 = xb + (size_t)(toks[192 + rr] >> 1) * D_DIM + coff;
  const unsigned short* bp0 = bpanel + (size_t)rr * D_DIM + coff;
  const unsigned short* bp1 = bpanel + (size_t)(64 + rr) * D_DIM + coff;
  const unsigned short* bp2 = bpanel + (size_t)(128 + rr) * D_DIM + coff;
  const unsigned short* bp3 = bpanel + (size_t)(192 + rr) * D_DIM + coff;
  int wr = w >> 2, wc = w & 3;           // 2 x 4 wave grid, tile 128x64
  int lr = lane & 15, lc = lane >> 4;
  int aoff[8], boff[4];
#pragma unroll
  for (int m = 0; m < 8; ++m) {
    int row = wr * 128 + m * 16 + lr;
    aoff[m] = row * 64 + ((lc ^ (row & 7)) * 8);
  }
#pragma unroll
  for (int n = 0; n < 4; ++n) {
    int row = wc * 64 + n * 16 + lr;
    boff[n] = row * 64 + ((lc ^ (row & 7)) * 8);
  }
  f32x4 acc[8][4] = {};
  // prologue: stage tiles 0 and 1; counted wait leaves tile 1 in flight
  async16(ap0, &As[0][tid * 8]);        async16(ap1, &As[0][4096 + tid * 8]);
  async16(ap2, &As[0][8192 + tid * 8]); async16(ap3, &As[0][12288 + tid * 8]);
  async16(bp0, &Bs[0][tid * 8]);        async16(bp1, &Bs[0][4096 + tid * 8]);
  async16(bp2, &Bs[0][8192 + tid * 8]); async16(bp3, &Bs[0][12288 + tid * 8]);
  async16(ap0 + 64, &As[1][tid * 8]);        async16(ap1 + 64, &As[1][4096 + tid * 8]);
  async16(ap2 + 64, &As[1][8192 + tid * 8]); async16(ap3 + 64, &As[1][12288 + tid * 8]);
  async16(bp0 + 64, &Bs[1][tid * 8]);        async16(bp1 + 64, &Bs[1][4096 + tid * 8]);
  async16(bp2 + 64, &Bs[1][8192 + tid * 8]); async16(bp3 + 64, &Bs[1][12288 + tid * 8]);
  asm volatile("s_waitcnt vmcnt(8)" ::: "memory");
  __builtin_amdgcn_s_barrier();
  for (int kt = 0; kt < 14; kt += 2) {   // tiles 0..13 (NK=16)
    G_ITER(0, kt + 2, 1, "8")
    G_ITER(1, kt + 3, 1, "8")
  }
  G_ITER(0, 16, 0, "0")                  // tile 14
  G_ITER(1, 17, 0, "0")                  // tile 15

  int g4 = lane >> 4, cl = lane & 15;
  int fbase = (4 * ft + wc) * 32;   // 32 f-cols per wave (w1 n=0,1 ; w3 n=2,3)
#pragma unroll
  for (int m = 0; m < 8; ++m) {
#pragma unroll
    for (int j = 0; j < 4; ++j) {
      int rloc = wr * 128 + m * 16 + g4 * 4 + j;
      if (r0 + rloc < ne) {
        unsigned short* hp = H + (size_t)toks[rloc] * F_DIM + fbase + cl;
#pragma unroll
        for (int n = 0; n < 2; ++n) {
          float c1 = acc[m][n][j], c3 = acc[m][n + 2][j];
          float h = c1 / (1.0f + __expf(-c1)) * c3;
          hp[n * 16] = f2bf(h);
        }
      }
    }
  }
}

// ---- GEMM2: out += w * (He @ W2e). 256x256, 8 waves, counted-vmcnt ----
__global__ __launch_bounds__(512, 2) void gemm2_kernel(
    const unsigned short* __restrict__ H, const unsigned short* __restrict__ w2t,
    const int* __restrict__ cnt, const int* __restrict__ ilist,
    const float* __restrict__ wlist, float* __restrict__ out) {
  int flat = blockIdx.x;       // 1024 blocks
  int e = flat & 7;
  int work = flat >> 3;
  int rt = work & 31;
  int nt = work >> 5;          // 0..3
  int ne = cnt[e];
  int r0 = rt * 256;
  if (r0 >= ne) return;
  __shared__ __align__(16) unsigned short As[2][16384];
  __shared__ __align__(16) unsigned short Bs[2][16384];
  __shared__ int toks[256];
  __shared__ float wts[256];
  int tid = threadIdx.x, lane = tid & 63, w = tid >> 6;
  if (tid < 256) {
    int idx = e * T_TOK + min(r0 + tid, ne - 1);
    toks[tid] = ilist[idx];
    wts[tid] = wlist[idx];
  }
  __syncthreads();
  const unsigned short* bpanel = w2t + ((size_t)e * D_DIM + nt * 256) * F_DIM;
  int rr = tid >> 3, ch = tid & 7;
  int coff = ((ch ^ (rr & 7)) * 8);
  const unsigned short* ap0 = H + (size_t)toks[rr] * F_DIM + coff;
  const unsigned short* ap1 = H + (size_t)toks[64 + rr] * F_DIM + coff;
  const unsigned short* ap2 = H + (size_t)toks[128 + rr] * F_DIM + coff;
  const unsigned short* ap3 = H + (size_t)toks[192 + rr] * F_DIM + coff;
  const unsigned short* bp0 = bpanel + (size_t)rr * F_DIM + coff;
  const unsigned short* bp1 = bpanel + (size_t)(64 + rr) * F_DIM + coff;
  const unsigned short* bp2 = bpanel + (size_t)(128 + rr) * F_DIM + coff;
  const unsigned short* bp3 = bpanel + (size_t)(192 + rr) * F_DIM + coff;
  int wr = w >> 2, wc = w & 3;
  int lr = lane & 15, lc = lane >> 4;
  int aoff[8], boff[4];
#pragma unroll
  for (int m = 0; m < 8; ++m) {
    int row = wr * 128 + m * 16 + lr;
    aoff[m] = row * 64 + ((lc ^ (row & 7)) * 8);
  }
#pragma unroll
  for (int n = 0; n < 4; ++n) {
    int row = wc * 64 + n * 16 + lr;
    boff[n] = row * 64 + ((lc ^ (row & 7)) * 8);
  }
  f32x4 acc[8][4] = {};
  async16(ap0, &As[0][tid * 8]);        async16(ap1, &As[0][4096 + tid * 8]);
  async16(ap2, &As[0][8192 + tid * 8]); async16(ap3, &As[0][12288 + tid * 8]);
  async16(bp0, &Bs[0][tid * 8]);        async16(bp1, &Bs[0][4096 + tid * 8]);
  async16(bp2, &Bs[0][8192 + tid * 8]); async16(bp3, &Bs[0][12288 + tid * 8]);
  async16(ap0 + 64, &As[1][tid * 8]);        async16(ap1 + 64, &As[1][4096 + tid * 8]);
  async16(ap2 + 64, &As[1][8192 + tid * 8]); async16(ap3 + 64, &As[1][12288 + tid * 8]);
  async16(bp0 + 64, &Bs[1][tid * 8]);        async16(bp1 + 64, &Bs[1][4096 + tid * 8]);
  async16(bp2 + 64, &Bs[1][8192 + tid * 8]); async16(bp3 + 64, &Bs[1][12288 + tid * 8]);
  asm volatile("s_waitcnt vmcnt(8)" ::: "memory");
  __builtin_amdgcn_s_barrier();
  for (int kt = 0; kt < 62; kt += 2) {   // tiles 0..61 (NK=64)
    G_ITER(0, kt + 2, 1, "8")
    G_ITER(1, kt + 3, 1, "8")
  }
  G_ITER(0, 64, 0, "0")                  // tile 62
  G_ITER(1, 65, 0, "0")                  // tile 63

  int g4 = lane >> 4, cl = lane & 15;
#pragma unroll
  for (int m = 0; m < 8; ++m) {
#pragma unroll
    for (int j = 0; j < 4; ++j) {
      int rloc = wr * 128 + m * 16 + g4 * 4 + j;
      if (r0 + rloc < ne) {
        int tok = toks[rloc] >> 1;
        float ww = wts[rloc];
        float* op = out + (size_t)tok * D_DIM + nt * 256 + wc * 64 + cl;
#pragma unroll
        for (int n = 0; n < 4; ++n)
          unsafeAtomicAdd(op + n * 16, ww * acc[m][n][j]);
      }
    }
  }
}

extern "C" void kernel_launch(void* const* d_in, const int* in_sizes, int n_in,
                              void* d_out, int out_size, void* d_ws, size_t ws_size,
                              hipStream_t stream) {
  const float* hs = (const float*)d_in[0];
  const float* nw = (const float*)d_in[1];
  const float* gw = (const float*)d_in[2];
  const float* w1 = (const float*)d_in[3];
  const float* w3 = (const float*)d_in[4];
  const float* w2 = (const float*)d_in[5];
  float* out = (float*)d_out;
  float* logits_out = out + (size_t)T_TOK * D_DIM;

  char* ws = (char*)d_ws;
  unsigned short* xb   = (unsigned short*)(ws);                 // 16 MiB bf16 x
  unsigned short* w13t = (unsigned short*)(ws + 16777216ull);   // 128 MiB [E][8192][D]
  unsigned short* w2t  = (unsigned short*)(ws + 150994944ull);  // 64 MiB [E][D][F]
  unsigned short* H    = (unsigned short*)(ws + 218103808ull);  // 128 MiB [2T][F]
  int*   ilist = (int*)(ws + 352321536ull);                     // [E][T] int
  float* wlist = (float*)(ws + 352583680ull);                   // [E][T] f32
  int*   cnt   = (int*)(ws + 352845824ull);                     // [E] int

  hipMemsetAsync(d_out, 0, (size_t)out_size * sizeof(float), stream);
  hipMemsetAsync(cnt, 0, E_NUM * sizeof(int), stream);
  norm_router_kernel<<<T_TOK, 256, 0, stream>>>(hs, nw, gw, xb, logits_out, cnt, ilist, wlist);
  transpose_cvt_kernel<<<3 * E_NUM * 1024, 256, 0, stream>>>(w1, w3, w2, w13t, w2t);
  gemm1_kernel<<<E_NUM * 32 * 32, 512, 0, stream>>>(xb, w13t, H, cnt, ilist);
  gemm2_kernel<<<E_NUM * 32 * 4, 512, 0, stream>>>(H, w2t, cnt, ilist, wlist, out);
}

// Round 8
// 929.787 us; speedup vs baseline: 1.0933x; 1.0848x over previous
//
#include <hip/hip_runtime.h>
#include <hip/hip_bf16.h>

#define T_TOK 8192
#define D_DIM 1024
#define F_DIM 4096
#define E_NUM 8

typedef short s16x8 __attribute__((ext_vector_type(8)));
typedef float f32x4 __attribute__((ext_vector_type(4)));
typedef unsigned short u16x8 __attribute__((ext_vector_type(8)));

__device__ __forceinline__ unsigned short f2bf(float f) {
  union { float f; unsigned int u; } v; v.f = f;
  unsigned int u = v.u;
  return (unsigned short)((u + 0x7FFFu + ((u >> 16) & 1u)) >> 16);  // RNE
}

__device__ __forceinline__ void async16(const void* g, void* l) {
  __builtin_amdgcn_global_load_lds((const __attribute__((address_space(1))) void*)g,
                                   (__attribute__((address_space(3))) void*)l, 16, 0, 0);
}

// ---------------- RMSNorm + router (fp32) + top-2 compaction ----------------
__global__ __launch_bounds__(256) void norm_router_kernel(
    const float* __restrict__ hs, const float* __restrict__ nw,
    const float* __restrict__ gw, unsigned short* __restrict__ xb,
    float* __restrict__ logits_out, int* __restrict__ cnt,
    int* __restrict__ ilist, float* __restrict__ wlist) {
  int t = blockIdx.x;
  int tid = threadIdx.x;
  int lane = tid & 63, wid = tid >> 6;
  float4 v = ((const float4*)(hs + (size_t)t * D_DIM))[tid];
  float ss = v.x * v.x + v.y * v.y + v.z * v.z + v.w * v.w;
#pragma unroll
  for (int o = 32; o > 0; o >>= 1) ss += __shfl_xor(ss, o);
  __shared__ float red[4];
  __shared__ float pl[4][8];
  if (lane == 0) red[wid] = ss;
  __syncthreads();
  float ms = (red[0] + red[1] + red[2] + red[3]) * (1.0f / 1024.0f);
  float rs = rsqrtf(ms + 1e-6f);
  float4 wv = ((const float4*)nw)[tid];
  float x0 = v.x * rs * wv.x, x1 = v.y * rs * wv.y;
  float x2 = v.z * rs * wv.z, x3 = v.w * rs * wv.w;
  ((ushort4*)(xb + (size_t)t * D_DIM))[tid] =
      make_ushort4(f2bf(x0), f2bf(x1), f2bf(x2), f2bf(x3));
  float p[8];
#pragma unroll
  for (int e = 0; e < 8; ++e) {
    float4 g = ((const float4*)(gw + (size_t)e * D_DIM))[tid];
    p[e] = x0 * g.x + x1 * g.y + x2 * g.z + x3 * g.w;
  }
#pragma unroll
  for (int e = 0; e < 8; ++e) {
#pragma unroll
    for (int o = 32; o > 0; o >>= 1) p[e] += __shfl_xor(p[e], o);
  }
  if (lane == 0) {
#pragma unroll
    for (int e = 0; e < 8; ++e) pl[wid][e] = p[e];
  }
  __syncthreads();
  if (tid == 0) {
    float l[8];
#pragma unroll
    for (int e = 0; e < 8; ++e) {
      l[e] = pl[0][e] + pl[1][e] + pl[2][e] + pl[3][e];
      logits_out[(size_t)t * 8 + e] = l[e];
    }
    int i0 = 0; float b0 = l[0];
#pragma unroll
    for (int e = 1; e < 8; ++e) if (l[e] > b0) { b0 = l[e]; i0 = e; }
    int i1 = (i0 == 0) ? 1 : 0; float b1 = l[i1];
#pragma unroll
    for (int e = 0; e < 8; ++e) if (e != i0 && l[e] > b1) { b1 = l[e]; i1 = e; }
    float wa = 1.0f / (1.0f + __expf(b1 - b0));
    float wb = 1.0f / (1.0f + __expf(b0 - b1));
    int p0 = atomicAdd(&cnt[i0], 1);
    ilist[i0 * T_TOK + p0] = t * 2;     wlist[i0 * T_TOK + p0] = wa;
    int p1 = atomicAdd(&cnt[i1], 1);
    ilist[i1 * T_TOK + p1] = t * 2 + 1; wlist[i1 * T_TOK + p1] = wb;
  }
}

// ---- weight f32 -> bf16 transpose. w1/w3 -> w13t[e][8192][D] with 32-col
// ---- interleave; w2 -> w2t[e][D][F]
__global__ __launch_bounds__(256) void transpose_cvt_kernel(
    const float* __restrict__ w1, const float* __restrict__ w3,
    const float* __restrict__ w2, unsigned short* __restrict__ w13t,
    unsigned short* __restrict__ w2t) {
  __shared__ unsigned short tileS[64][72];  // [c-local][r-local], padded
  int bx = blockIdx.x;
  int tensor = bx >> 13;
  int e = (bx >> 10) & 7;
  int tl = bx & 1023;
  const float* src; int C, tr, tc;
  if (tensor == 0) {
    src = w1 + (size_t)e * D_DIM * F_DIM; C = F_DIM; tr = tl >> 6; tc = tl & 63;
  } else if (tensor == 1) {
    src = w3 + (size_t)e * D_DIM * F_DIM; C = F_DIM; tr = tl >> 6; tc = tl & 63;
  } else {
    src = w2 + (size_t)e * F_DIM * D_DIM; C = D_DIM; tr = tl >> 4; tc = tl & 15;
  }
  int r0 = tr * 64, c0 = tc * 64;
  int tid = threadIdx.x;
  int rr = tid >> 4, ccb = (tid & 15) * 4;
#pragma unroll
  for (int i = 0; i < 4; ++i) {
    int r = rr + i * 16;
    float4 v = *(const float4*)(src + (size_t)(r0 + r) * C + c0 + ccb);
    tileS[ccb + 0][r] = f2bf(v.x);
    tileS[ccb + 1][r] = f2bf(v.y);
    tileS[ccb + 2][r] = f2bf(v.z);
    tileS[ccb + 3][r] = f2bf(v.w);
  }
  __syncthreads();
  int row = tid >> 2, col = (tid & 3) * 16;
  unsigned short* dp;
  if (tensor < 2) {
    int f = c0 + row;
    int prow = ((f >> 5) * 64) + (f & 31) + (tensor == 1 ? 32 : 0);
    dp = w13t + ((size_t)e * 8192 + prow) * D_DIM + r0 + col;
  } else {
    dp = w2t + ((size_t)e * D_DIM + c0 + row) * F_DIM + r0 + col;
  }
  u16x8 v0, v1;
#pragma unroll
  for (int j = 0; j < 8; ++j) { v0[j] = tileS[row][col + j]; v1[j] = tileS[row][col + 8 + j]; }
  *(u16x8*)dp = v0;
  *(u16x8*)(dp + 8) = v1;
}

// ---- shared MFMA helper: 4 MFMAs of one A-frag against b0..b3 ----
#define MFMA4(AI_, M_)                                                           \
  acc[M_][0] = __builtin_amdgcn_mfma_f32_16x16x32_bf16(AI_, b0, acc[M_][0], 0, 0, 0); \
  acc[M_][1] = __builtin_amdgcn_mfma_f32_16x16x32_bf16(AI_, b1, acc[M_][1], 0, 0, 0); \
  acc[M_][2] = __builtin_amdgcn_mfma_f32_16x16x32_bf16(AI_, b2, acc[M_][2], 0, 0, 0); \
  acc[M_][3] = __builtin_amdgcn_mfma_f32_16x16x32_bf16(AI_, b3, acc[M_][3], 0, 0, 0);

#define LGKM0()                                                                  \
  asm volatile("s_waitcnt lgkmcnt(0)" ::: "memory");                             \
  __builtin_amdgcn_sched_barrier(0);

// ================= V0 control: r7 counted-vmcnt 8-phase (ft 0..7) =================
#define G_ITER(CUR_, KT2_, DOST_, VMC_)                                          \
  {                                                                              \
    const unsigned short* Ac = &As[CUR_][0];                                     \
    const unsigned short* Bc = &Bs[CUR_][0];                                     \
    s16x8 a0, a1, a2, a3, a4, a5, a6, a7, b0, b1, b2, b3, c0, c1, c2, c3;        \
    a0 = *(const s16x8*)(Ac + aoff[0]); a1 = *(const s16x8*)(Ac + aoff[1]);      \
    a2 = *(const s16x8*)(Ac + aoff[2]); a3 = *(const s16x8*)(Ac + aoff[3]);      \
    a4 = *(const s16x8*)(Ac + aoff[4]); a5 = *(const s16x8*)(Ac + aoff[5]);      \
    a6 = *(const s16x8*)(Ac + aoff[6]); a7 = *(const s16x8*)(Ac + aoff[7]);      \
    b0 = *(const s16x8*)(Bc + boff[0]); b1 = *(const s16x8*)(Bc + boff[1]);      \
    b2 = *(const s16x8*)(Bc + boff[2]); b3 = *(const s16x8*)(Bc + boff[3]);      \
    __builtin_amdgcn_s_barrier();                                                \
    LGKM0()                                                                      \
    __builtin_amdgcn_s_setprio(1);                                               \
    MFMA4(a0, 0) MFMA4(a1, 1) MFMA4(a2, 2) MFMA4(a3, 3)                          \
    __builtin_amdgcn_s_setprio(0);                                               \
    __builtin_amdgcn_s_barrier();                                                \
    c0 = *(const s16x8*)(Ac + (aoff[0] ^ 32)); c1 = *(const s16x8*)(Ac + (aoff[1] ^ 32)); \
    c2 = *(const s16x8*)(Ac + (aoff[2] ^ 32)); c3 = *(const s16x8*)(Ac + (aoff[3] ^ 32)); \
    __builtin_amdgcn_s_barrier();                                                \
    LGKM0()                                                                      \
    __builtin_amdgcn_s_setprio(1);                                               \
    MFMA4(a4, 4) MFMA4(a5, 5) MFMA4(a6, 6) MFMA4(a7, 7)                          \
    __builtin_amdgcn_s_setprio(0);                                               \
    __builtin_amdgcn_s_barrier();                                                \
    a4 = *(const s16x8*)(Ac + (aoff[4] ^ 32)); a5 = *(const s16x8*)(Ac + (aoff[5] ^ 32)); \
    a6 = *(const s16x8*)(Ac + (aoff[6] ^ 32)); a7 = *(const s16x8*)(Ac + (aoff[7] ^ 32)); \
    b0 = *(const s16x8*)(Bc + (boff[0] ^ 32)); b1 = *(const s16x8*)(Bc + (boff[1] ^ 32)); \
    b2 = *(const s16x8*)(Bc + (boff[2] ^ 32)); b3 = *(const s16x8*)(Bc + (boff[3] ^ 32)); \
    __builtin_amdgcn_s_barrier();                                                \
    LGKM0()                                                                      \
    __builtin_amdgcn_s_setprio(1);                                               \
    MFMA4(c0, 0) MFMA4(c1, 1) MFMA4(c2, 2) MFMA4(c3, 3)                          \
    __builtin_amdgcn_s_setprio(0);                                               \
    __builtin_amdgcn_s_barrier();                                                \
    if (DOST_) {                                                                 \
      int ko = (KT2_) * 64;                                                      \
      async16(ap0 + ko, &As[CUR_][tid * 8]);                                     \
      async16(ap1 + ko, &As[CUR_][4096 + tid * 8]);                              \
      async16(ap2 + ko, &As[CUR_][8192 + tid * 8]);                              \
      async16(ap3 + ko, &As[CUR_][12288 + tid * 8]);                             \
      async16(bp0 + ko, &Bs[CUR_][tid * 8]);                                     \
      async16(bp1 + ko, &Bs[CUR_][4096 + tid * 8]);                              \
      async16(bp2 + ko, &Bs[CUR_][8192 + tid * 8]);                              \
      async16(bp3 + ko, &Bs[CUR_][12288 + tid * 8]);                             \
    }                                                                            \
    __builtin_amdgcn_s_setprio(1);                                               \
    MFMA4(a4, 4) MFMA4(a5, 5) MFMA4(a6, 6) MFMA4(a7, 7)                          \
    __builtin_amdgcn_s_setprio(0);                                               \
    asm volatile("s_waitcnt vmcnt(" VMC_ ")" ::: "memory");                      \
    __builtin_amdgcn_s_barrier();                                                \
  }

__global__ __launch_bounds__(512, 2) void gemm1_v0_kernel(
    const unsigned short* __restrict__ xb, const unsigned short* __restrict__ w13t,
    unsigned short* __restrict__ H, const int* __restrict__ cnt,
    const int* __restrict__ ilist) {
  int flat = blockIdx.x;       // 2048 blocks: e(8) x rt(32) x ft(8)
  int e = flat & 7;
  int work = flat >> 3;
  int rt = work & 31;
  int ft = work >> 5;          // 0..7
  int ne = cnt[e];
  int r0 = rt * 256;
  if (r0 >= ne) return;
  __shared__ __align__(16) unsigned short As[2][16384];
  __shared__ __align__(16) unsigned short Bs[2][16384];
  __shared__ int toks[256];
  int tid = threadIdx.x, lane = tid & 63, w = tid >> 6;
  if (tid < 256) toks[tid] = ilist[e * T_TOK + min(r0 + tid, ne - 1)];
  __syncthreads();
  const unsigned short* bpanel = w13t + ((size_t)e * 8192 + ft * 256) * D_DIM;
  int rr = tid >> 3, ch = tid & 7;
  int coff = ((ch ^ (rr & 7)) * 8);
  const unsigned short* ap0 = xb + (size_t)(toks[rr] >> 1) * D_DIM + coff;
  const unsigned short* ap1 = xb + (size_t)(toks[64 + rr] >> 1) * D_DIM + coff;
  const unsigned short* ap2 = xb + (size_t)(toks[128 + rr] >> 1) * D_DIM + coff;
  const unsigned short* ap3 = xb + (size_t)(toks[192 + rr] >> 1) * D_DIM + coff;
  const unsigned short* bp0 = bpanel + (size_t)rr * D_DIM + coff;
  const unsigned short* bp1 = bpanel + (size_t)(64 + rr) * D_DIM + coff;
  const unsigned short* bp2 = bpanel + (size_t)(128 + rr) * D_DIM + coff;
  const unsigned short* bp3 = bpanel + (size_t)(192 + rr) * D_DIM + coff;
  int wr = w >> 2, wc = w & 3;
  int lr = lane & 15, lc = lane >> 4;
  int aoff[8], boff[4];
#pragma unroll
  for (int m = 0; m < 8; ++m) {
    int row = wr * 128 + m * 16 + lr;
    aoff[m] = row * 64 + ((lc ^ (row & 7)) * 8);
  }
#pragma unroll
  for (int n = 0; n < 4; ++n) {
    int row = wc * 64 + n * 16 + lr;
    boff[n] = row * 64 + ((lc ^ (row & 7)) * 8);
  }
  f32x4 acc[8][4] = {};
  async16(ap0, &As[0][tid * 8]);        async16(ap1, &As[0][4096 + tid * 8]);
  async16(ap2, &As[0][8192 + tid * 8]); async16(ap3, &As[0][12288 + tid * 8]);
  async16(bp0, &Bs[0][tid * 8]);        async16(bp1, &Bs[0][4096 + tid * 8]);
  async16(bp2, &Bs[0][8192 + tid * 8]); async16(bp3, &Bs[0][12288 + tid * 8]);
  async16(ap0 + 64, &As[1][tid * 8]);        async16(ap1 + 64, &As[1][4096 + tid * 8]);
  async16(ap2 + 64, &As[1][8192 + tid * 8]); async16(ap3 + 64, &As[1][12288 + tid * 8]);
  async16(bp0 + 64, &Bs[1][tid * 8]);        async16(bp1 + 64, &Bs[1][4096 + tid * 8]);
  async16(bp2 + 64, &Bs[1][8192 + tid * 8]); async16(bp3 + 64, &Bs[1][12288 + tid * 8]);
  asm volatile("s_waitcnt vmcnt(8)" ::: "memory");
  __builtin_amdgcn_s_barrier();
  for (int kt = 0; kt < 14; kt += 2) {
    G_ITER(0, kt + 2, 1, "8")
    G_ITER(1, kt + 3, 1, "8")
  }
  G_ITER(0, 16, 0, "0")
  G_ITER(1, 17, 0, "0")

  int g4 = lane >> 4, cl = lane & 15;
  int fbase = (4 * ft + wc) * 32;
#pragma unroll
  for (int m = 0; m < 8; ++m) {
#pragma unroll
    for (int j = 0; j < 4; ++j) {
      int rloc = wr * 128 + m * 16 + g4 * 4 + j;
      if (r0 + rloc < ne) {
        unsigned short* hp = H + (size_t)toks[rloc] * F_DIM + fbase + cl;
#pragma unroll
        for (int n = 0; n < 2; ++n) {
          float c1 = acc[m][n][j], c3 = acc[m][n + 2][j];
          float h = c1 / (1.0f + __expf(-c1)) * c3;
          hp[n * 16] = f2bf(h);
        }
      }
    }
  }
}
#undef G_ITER

// ================= m97-style quarter kernels (V1/V2/V3) =================
// 128x128 tile, 4 waves 64x64, BK=64. DBUF: 0=single-buf (m97), 1=double-buf.
// XPIN: 1=expert pinned to XCD (e=flat&7), 0=expert from high bits.
#define STG(BUF_, KO_)                                                           \
  async16(as0 + (KO_), &As[BUF_][st0 + lane * 8]);                               \
  async16(as1 + (KO_), &As[BUF_][st1 + lane * 8]);                               \
  async16(as2 + (KO_), &As[BUF_][st2 + lane * 8]);                               \
  async16(as3 + (KO_), &As[BUF_][st3 + lane * 8]);                               \
  async16(bs0 + (KO_), &Bs[BUF_][st0 + lane * 8]);                               \
  async16(bs1 + (KO_), &Bs[BUF_][st1 + lane * 8]);                               \
  async16(bs2 + (KO_), &Bs[BUF_][st2 + lane * 8]);                               \
  async16(bs3 + (KO_), &Bs[BUF_][st3 + lane * 8]);

#define CMP(BUF_)                                                                \
  {                                                                              \
    const unsigned short* Ac = &As[BUF_][0];                                     \
    const unsigned short* Bc = &Bs[BUF_][0];                                     \
    s16x8 a0, a1, a2, a3, b0, b1, b2, b3;                                        \
    a0 = *(const s16x8*)(Ac + aoff0); a1 = *(const s16x8*)(Ac + aoff1);          \
    a2 = *(const s16x8*)(Ac + aoff2); a3 = *(const s16x8*)(Ac + aoff3);          \
    b0 = *(const s16x8*)(Bc + boff0); b1 = *(const s16x8*)(Bc + boff1);          \
    b2 = *(const s16x8*)(Bc + boff2); b3 = *(const s16x8*)(Bc + boff3);          \
    MFMA4(a0, 0) MFMA4(a1, 1) MFMA4(a2, 2) MFMA4(a3, 3)                          \
    a0 = *(const s16x8*)(Ac + (aoff0 ^ 32)); a1 = *(const s16x8*)(Ac + (aoff1 ^ 32)); \
    a2 = *(const s16x8*)(Ac + (aoff2 ^ 32)); a3 = *(const s16x8*)(Ac + (aoff3 ^ 32)); \
    b0 = *(const s16x8*)(Bc + (boff0 ^ 32)); b1 = *(const s16x8*)(Bc + (boff1 ^ 32)); \
    b2 = *(const s16x8*)(Bc + (boff2 ^ 32)); b3 = *(const s16x8*)(Bc + (boff3 ^ 32)); \
    MFMA4(a0, 0) MFMA4(a1, 1) MFMA4(a2, 2) MFMA4(a3, 3)                          \
  }

template <int DBUF, int XPIN>
__global__ __launch_bounds__(256, 3) void gemm1_m97_kernel(
    const unsigned short* __restrict__ xb, const unsigned short* __restrict__ w13t,
    unsigned short* __restrict__ H, const int* __restrict__ cnt,
    const int* __restrict__ ilist, int Q) {
  int flat = blockIdx.x;  // 2560 blocks: e(8) x rt(20) x ftg(16)
  int e, work;
  if (XPIN) { e = flat & 7; work = flat >> 3; }
  else      { e = flat / 320; work = flat % 320; }
  int ftg = work & 15;
  int rt = work >> 4;     // 0..19
  int ne = cnt[e];
  int r0 = rt * 128;
  if (r0 >= ne) return;
  __shared__ __align__(16) unsigned short As[DBUF ? 2 : 1][8192];  // [128][64]
  __shared__ __align__(16) unsigned short Bs[DBUF ? 2 : 1][8192];
  __shared__ int toks[128];
  int tid = threadIdx.x, lane = tid & 63, w = tid >> 6;
  if (tid < 128) toks[tid] = ilist[e * T_TOK + min(r0 + tid, ne - 1)];
  __syncthreads();
  int pbase = Q * 2048 + ftg * 128;
  const unsigned short* bpanel = w13t + ((size_t)e * 8192 + pbase) * D_DIM;
  // staging: wave w call j covers rows (w*4+j)*8 + (lane>>3), chunk lane&7
  int ch = lane & 7;
  int r0s = (w * 4 + 0) * 8 + (lane >> 3), c0s = ((ch ^ (r0s & 7)) * 8);
  int r1s = (w * 4 + 1) * 8 + (lane >> 3), c1s = ((ch ^ (r1s & 7)) * 8);
  int r2s = (w * 4 + 2) * 8 + (lane >> 3), c2s = ((ch ^ (r2s & 7)) * 8);
  int r3s = (w * 4 + 3) * 8 + (lane >> 3), c3s = ((ch ^ (r3s & 7)) * 8);
  const unsigned short* as0 = xb + (size_t)(toks[r0s] >> 1) * D_DIM + c0s;
  const unsigned short* as1 = xb + (size_t)(toks[r1s] >> 1) * D_DIM + c1s;
  const unsigned short* as2 = xb + (size_t)(toks[r2s] >> 1) * D_DIM + c2s;
  const unsigned short* as3 = xb + (size_t)(toks[r3s] >> 1) * D_DIM + c3s;
  const unsigned short* bs0 = bpanel + (size_t)r0s * D_DIM + c0s;
  const unsigned short* bs1 = bpanel + (size_t)r1s * D_DIM + c1s;
  const unsigned short* bs2 = bpanel + (size_t)r2s * D_DIM + c2s;
  const unsigned short* bs3 = bpanel + (size_t)r3s * D_DIM + c3s;
  int st0 = (w * 4 + 0) * 512, st1 = (w * 4 + 1) * 512;
  int st2 = (w * 4 + 2) * 512, st3 = (w * 4 + 3) * 512;
  int wr = w >> 1, wc = w & 1;  // 2x2 wave grid, 64x64 tiles
  int lr = lane & 15, lc = lane >> 4;
  int row;
  row = wr * 64 + 0 * 16 + lr;  int aoff0 = row * 64 + ((lc ^ (row & 7)) * 8);
  row = wr * 64 + 1 * 16 + lr;  int aoff1 = row * 64 + ((lc ^ (row & 7)) * 8);
  row = wr * 64 + 2 * 16 + lr;  int aoff2 = row * 64 + ((lc ^ (row & 7)) * 8);
  row = wr * 64 + 3 * 16 + lr;  int aoff3 = row * 64 + ((lc ^ (row & 7)) * 8);
  row = wc * 64 + 0 * 16 + lr;  int boff0 = row * 64 + ((lc ^ (row & 7)) * 8);
  row = wc * 64 + 1 * 16 + lr;  int boff1 = row * 64 + ((lc ^ (row & 7)) * 8);
  row = wc * 64 + 2 * 16 + lr;  int boff2 = row * 64 + ((lc ^ (row & 7)) * 8);
  row = wc * 64 + 3 * 16 + lr;  int boff3 = row * 64 + ((lc ^ (row & 7)) * 8);
  f32x4 acc[4][4] = {};
  if (DBUF == 0) {
    // m97: single buffer, stage -> sync -> compute -> sync
#pragma unroll 1
    for (int kt = 0; kt < 16; ++kt) {
      STG(0, kt * 64)
      __syncthreads();
      CMP(0)
      __syncthreads();
    }
  } else {
    STG(0, 0)
    __syncthreads();
#pragma unroll 2
    for (int kt = 0; kt < 16; ++kt) {
      if (kt < 15) {
        if (kt & 1) { STG(0, (kt + 1) * 64) } else { STG(1, (kt + 1) * 64) }
      }
      if (kt & 1) { CMP(1) } else { CMP(0) }
      __syncthreads();
    }
  }
  int g4 = lane >> 4, cl = lane & 15;
  int fb = (pbase >> 1) + wc * 32;
#pragma unroll
  for (int m = 0; m < 4; ++m) {
#pragma unroll
    for (int j = 0; j < 4; ++j) {
      int rloc = wr * 64 + m * 16 + g4 * 4 + j;
      if (r0 + rloc < ne) {
        unsigned short* hp = H + (size_t)toks[rloc] * F_DIM + fb + cl;
#pragma unroll
        for (int n = 0; n < 2; ++n) {
          float c1 = acc[m][n][j], c3 = acc[m][n + 2][j];
          float h = c1 / (1.0f + __expf(-c1)) * c3;
          hp[n * 16] = f2bf(h);
        }
      }
    }
  }
}
#undef STG
#undef CMP

// ================= GEMM2 (round-5 version, unchanged) =================
__global__ __launch_bounds__(512, 2) void gemm2_kernel(
    const unsigned short* __restrict__ H, const unsigned short* __restrict__ w2t,
    const int* __restrict__ cnt, const int* __restrict__ ilist,
    const float* __restrict__ wlist, float* __restrict__ out) {
  int flat = blockIdx.x;       // 1024 blocks
  int e = flat & 7;
  int work = flat >> 3;
  int rt = work & 31;
  int nt = work >> 5;          // 0..3
  int ne = cnt[e];
  int r0 = rt * 256;
  if (r0 >= ne) return;
  __shared__ __align__(16) unsigned short As[3 * 8192];
  __shared__ __align__(16) unsigned short Bs[3 * 8192];
  __shared__ int toks[256];
  __shared__ float wts[256];
  int tid = threadIdx.x, lane = tid & 63, w = tid >> 6;
  if (tid < 256) {
    int idx = e * T_TOK + min(r0 + tid, ne - 1);
    toks[tid] = ilist[idx];
    wts[tid] = wlist[idx];
  }
  __syncthreads();
  const unsigned short* bpanel = w2t + ((size_t)e * D_DIM + nt * 256) * F_DIM;
  int sr0 = tid >> 2, sr1 = sr0 + 128;
  int ch0 = (((tid & 3) ^ ((sr0 >> 1) & 3)) * 8);
  int ch1 = (((tid & 3) ^ ((sr1 >> 1) & 3)) * 8);
  const unsigned short* ap0 = H + (size_t)toks[sr0] * F_DIM + ch0;
  const unsigned short* ap1 = H + (size_t)toks[sr1] * F_DIM + ch1;
  const unsigned short* bp0 = bpanel + (size_t)sr0 * F_DIM + ch0;
  const unsigned short* bp1 = bpanel + (size_t)sr1 * F_DIM + ch1;
  int d0 = (sr0 * 32) + (tid & 3) * 8;
  int d1 = d0 + 4096;
  int wr = w >> 2, wc = w & 3;
  int lr = lane & 15, lc = lane >> 4;
  int aoff[8], boff[4];
#pragma unroll
  for (int m = 0; m < 8; ++m) {
    int row = wr * 128 + m * 16 + lr;
    aoff[m] = row * 32 + ((lc ^ ((row >> 1) & 3)) * 8);
  }
#pragma unroll
  for (int n = 0; n < 4; ++n) {
    int row = wc * 64 + n * 16 + lr;
    boff[n] = row * 32 + ((lc ^ ((row >> 1) & 3)) * 8);
  }
  f32x4 acc[8][4] = {};
  async16(ap0, &As[d0]); async16(ap1, &As[d1]);
  async16(bp0, &Bs[d0]); async16(bp1, &Bs[d1]);
  async16(ap0 + 32, &As[8192 + d0]); async16(ap1 + 32, &As[8192 + d1]);
  async16(bp0 + 32, &Bs[8192 + d0]); async16(bp1 + 32, &Bs[8192 + d1]);

#define G2_STEP(T_, BUF_, VMC_, DOST_)                                          \
  {                                                                             \
    asm volatile("s_waitcnt vmcnt(" VMC_ ")" ::: "memory");                     \
    __builtin_amdgcn_s_barrier();                                               \
    const unsigned short* Ab = &As[(BUF_) * 8192];                              \
    const unsigned short* Bb = &Bs[(BUF_) * 8192];                              \
    s16x8 a[8], b[4];                                                           \
    if (DOST_) {                                                                \
      int nk = ((T_) + 2) * 32;                                                 \
      async16(ap0 + nk, &As[(((BUF_) + 2) % 3) * 8192 + d0]);                   \
      async16(ap1 + nk, &As[(((BUF_) + 2) % 3) * 8192 + d1]);                   \
    }                                                                           \
    _Pragma("unroll") for (int m = 0; m < 4; ++m)                               \
        a[m] = *(const s16x8*)(Ab + aoff[m]);                                   \
    _Pragma("unroll") for (int n = 0; n < 4; ++n)                               \
        b[n] = *(const s16x8*)(Bb + boff[n]);                                   \
    __builtin_amdgcn_s_setprio(1);                                              \
    _Pragma("unroll") for (int m = 0; m < 4; ++m)                               \
        _Pragma("unroll") for (int n = 0; n < 4; ++n)                           \
            acc[m][n] = __builtin_amdgcn_mfma_f32_16x16x32_bf16(                \
                a[m], b[n], acc[m][n], 0, 0, 0);                                \
    __builtin_amdgcn_s_setprio(0);                                              \
    if (DOST_) {                                                                \
      int nk = ((T_) + 2) * 32;                                                 \
      async16(bp0 + nk, &Bs[(((BUF_) + 2) % 3) * 8192 + d0]);                   \
      async16(bp1 + nk, &Bs[(((BUF_) + 2) % 3) * 8192 + d1]);                   \
    }                                                                           \
    _Pragma("unroll") for (int m = 4; m < 8; ++m)                               \
        a[m] = *(const s16x8*)(Ab + aoff[m]);                                   \
    __builtin_amdgcn_s_setprio(1);                                              \
    _Pragma("unroll") for (int m = 4; m < 8; ++m)                               \
        _Pragma("unroll") for (int n = 0; n < 4; ++n)                           \
            acc[m][n] = __builtin_amdgcn_mfma_f32_16x16x32_bf16(                \
                a[m], b[n], acc[m][n], 0, 0, 0);                                \
    __builtin_amdgcn_s_setprio(0);                                              \
  }

  for (int tb = 0; tb < 126; tb += 3) {
    G2_STEP(tb, 0, "4", 1)
    G2_STEP(tb + 1, 1, "4", 1)
    G2_STEP(tb + 2, 2, "4", 1)
  }
  G2_STEP(126, 0, "4", 0)
  G2_STEP(127, 1, "0", 0)
#undef G2_STEP

  int g4 = lane >> 4, cl = lane & 15;
#pragma unroll
  for (int m = 0; m < 8; ++m) {
#pragma unroll
    for (int j = 0; j < 4; ++j) {
      int rloc = wr * 128 + m * 16 + g4 * 4 + j;
      if (r0 + rloc < ne) {
        int tok = toks[rloc] >> 1;
        float ww = wts[rloc];
        float* op = out + (size_t)tok * D_DIM + nt * 256 + wc * 64 + cl;
#pragma unroll
        for (int n = 0; n < 4; ++n)
          unsafeAtomicAdd(op + n * 16, ww * acc[m][n][j]);
      }
    }
  }
}

extern "C" void kernel_launch(void* const* d_in, const int* in_sizes, int n_in,
                              void* d_out, int out_size, void* d_ws, size_t ws_size,
                              hipStream_t stream) {
  const float* hs = (const float*)d_in[0];
  const float* nw = (const float*)d_in[1];
  const float* gw = (const float*)d_in[2];
  const float* w1 = (const float*)d_in[3];
  const float* w3 = (const float*)d_in[4];
  const float* w2 = (const float*)d_in[5];
  float* out = (float*)d_out;
  float* logits_out = out + (size_t)T_TOK * D_DIM;

  char* ws = (char*)d_ws;
  unsigned short* xb   = (unsigned short*)(ws);                 // 16 MiB bf16 x
  unsigned short* w13t = (unsigned short*)(ws + 16777216ull);   // 128 MiB [E][8192][D]
  unsigned short* w2t  = (unsigned short*)(ws + 150994944ull);  // 64 MiB [E][D][F]
  unsigned short* H    = (unsigned short*)(ws + 218103808ull);  // 128 MiB [2T][F]
  int*   ilist = (int*)(ws + 352321536ull);                     // [E][T] int
  float* wlist = (float*)(ws + 352583680ull);                   // [E][T] f32
  int*   cnt   = (int*)(ws + 352845824ull);                     // [E] int

  hipMemsetAsync(d_out, 0, (size_t)out_size * sizeof(float), stream);
  hipMemsetAsync(cnt, 0, E_NUM * sizeof(int), stream);
  norm_router_kernel<<<T_TOK, 256, 0, stream>>>(hs, nw, gw, xb, logits_out, cnt, ilist, wlist);
  transpose_cvt_kernel<<<3 * E_NUM * 1024, 256, 0, stream>>>(w1, w3, w2, w13t, w2t);
  // ---- gemm1 split into 4 variant quarters (disjoint f ranges) ----
  gemm1_v0_kernel<<<E_NUM * 32 * 8, 512, 0, stream>>>(xb, w13t, H, cnt, ilist);
  gemm1_m97_kernel<0, 1><<<2560, 256, 0, stream>>>(xb, w13t, H, cnt, ilist, 1);
  gemm1_m97_kernel<1, 1><<<2560, 256, 0, stream>>>(xb, w13t, H, cnt, ilist, 2);
  gemm1_m97_kernel<0, 0><<<2560, 256, 0, stream>>>(xb, w13t, H, cnt, ilist, 3);
  gemm2_kernel<<<E_NUM * 32 * 4, 512, 0, stream>>>(H, w2t, cnt, ilist, wlist, out);
}